// Round 8
// baseline (228.018 us; speedup 1.0000x reference)
//
#include <hip/hip_runtime.h>
#include <hip/hip_fp16.h>

// CompatibilityLayer (R21 base + R22: sort-revert in k_bucket, fused reduce+Sinkhorn):
//   k_deg: range-binned LDS histograms (160KB LDS, R=3 x 80 slices; sniff flag aliased onto
//          h[0]); (r,sl)->blockIdx remap puts the 3 range-passes of one edge slice on the
//          SAME XCD (b%8) so passes 2-3 hit its 4MB L2. Block 0 zeros Hg/cnt/gCnt/done.
//   k_node: reduce deg slabs -> dinv; label/cnt/diag (masked); softmax -> p16 (unmasked);
//           ballot-packs the row mask into a global bitvector (1 bit/node)
//   k_bucket: stages 12.8KB mask bitvector in LDS; predicates the single ninfo[r] gather on
//             it. ALL active edges -> records {c<<5|a, dinv_r*w}; per-bucket span reserved
//             with ONE global atomic, then DIRECT scattered flush (R22: counting-sort removed
//             -- R18 proved scattered stores are posted/free; the sort's 18 barriers + 2 LDS
//             passes were pure overhead).
//   k_process: wave-0 ballot-scan compacts unmasked cols (~100 of 200); records * dinv_c
//              routed: masked col -> H32 tile, unmasked -> compacted TlocT; gemm over j<nU.
//   k_redsink (R22): 16 blocks reduce 513 slabs -> partials; last block (threadfence+atomic
//              counter) re-reads partials and runs Sinkhorn. Same summation order as the old
//              k_red+k_sinkhorn pair -> bitwise identical; saves one launch gap.
// Fixed ~100us/replay harness overhead (41us = 256MB workspace re-poison fill at 82% HBM).
// CALIBRATION (hard-won):
//   R15/R16: random divergent LOADS ~5.5-6us per 1M lane-transactions (the currency).
//   R18: scattered STORES are posted/free at ~50% occupancy -- coalescing them was a null.
//   R19: random GLOBAL ATOMICS ~52ns/op (3.2M = 167us!); each RMW write-throughs a line to
//        HBM. NEVER use global atomics for histograms; LDS-privatize. (One atomic per
//        (block,bucket) span reservation and one per reduction block is fine.)
//   R21: k_deg is DS-atomic/issue-bound, not scan-BW-bound -- byte-count levers null there.
// R14 lesson: deeper unrolls raise VGPR, drop occupancy, and REGRESS k_bucket.

#define RS 40960          // deg histogram range (160 KB LDS -- full CU, 1 block/CU in k_deg)
#define BDEG 80           // deg slices; k_deg grid = R*BDEG = 240 (R=3); 8 | R*BDEG required
#define W 200             // cols per bucket
#define NBKTMAX 512       // bucket slots (runtime nbkt = ceil(Nn/W) <= 512 for Nn <= 102400)
#define BCAP 4608         // per-bucket record capacity (avg ~3200, sd ~57, +24 sigma)
#define LCAP 4096         // per-block LDS record list (avg ~3125, sd ~40, +24 sigma)
#define NSC 512           // k_bucket blocks
#define NPR NBKTMAX       // k_process blocks
#define NTOT (1 + NPR)    // 513 slab copies: Hg | procSlab
#define NRED 16
#define RPER ((NTOT + NRED - 1) / NRED)
#define PPAD 204          // plocT stride in halfs (8B-aligned vectors, conflict-friendly)
#define BVW 3200          // mask bitvector words (covers Nn <= 102400 = NBKTMAX*W)

__global__ __launch_bounds__(1024) void
k_deg(const int* __restrict__ ei, const float* __restrict__ ew,
      __half* __restrict__ slab, const unsigned char* __restrict__ mask_bytes,
      int* __restrict__ flag, float* __restrict__ Hg, float* __restrict__ cnt,
      int* __restrict__ gCnt, int E_, int R, int Nn) {
  __shared__ float h[RS];              // exactly 160 KiB -- no other shared vars allowed
  if (blockIdx.x == 0) {
    Hg[threadIdx.x] = 0.f;
    if (threadIdx.x < 32) cnt[threadIdx.x] = 0.f;
    if (threadIdx.x < NBKTMAX) gCnt[threadIdx.x] = 0;
    // mask dtype sniff: int32 0/1 has zero bytes at i*4+{1,2,3}; bool byte-array doesn't.
    // Flag lives in h[0] (as int) -- sniff completes before the histogram zero pass.
    int* hi = (int*)h;
    if (threadIdx.x == 0) { hi[0] = 0; flag[4] = 0; }   // flag[4] = k_redsink done counter
    __syncthreads();
    int acc = mask_bytes[threadIdx.x * 4 + 1] | mask_bytes[threadIdx.x * 4 + 2]
            | mask_bytes[threadIdx.x * 4 + 3];
    if (acc) atomicOr(&hi[0], 1);
    __syncthreads();
    if (threadIdx.x == 0) *flag = (hi[0] != 0) ? 1 : 0;
  }
  // XCD-aware remap: the R blocks sharing edge slice sl get blockIdx == same value mod 8,
  // i.e. the same XCD under round-robin dispatch -> slice reads 2..R hit that XCD's L2.
  int g = blockIdx.x >> 3, xx = blockIdx.x & 7;
  int r = g % R;
  int sl = xx + 8 * (g / R);
  int lo = r * RS;
  int used = min(RS, Nn - lo);         // partial last range: only these bins are ever read
  for (int i = threadIdx.x; i < used; i += 1024) h[i] = 0.f;
  __syncthreads();
  int Q = E_ >> 2;
  int q0 = (int)((long long)Q * sl / BDEG);
  int q1 = (int)((long long)Q * (sl + 1) / BDEG);
  const int4* ei4 = (const int4*)ei;
  const float4* ew4 = (const float4*)ew;
  int q = q0 + threadIdx.x;
  for (; q + 1024 < q1; q += 2048) {       // 2-quad unroll: 8 edges in flight
    int4 ia = ei4[q], ib = ei4[q + 1024];
    float4 wa = ew4[q], wb = ew4[q + 1024];
    unsigned o0 = (unsigned)(ia.x - lo), o1 = (unsigned)(ia.y - lo);
    unsigned o2 = (unsigned)(ia.z - lo), o3 = (unsigned)(ia.w - lo);
    unsigned o4 = (unsigned)(ib.x - lo), o5 = (unsigned)(ib.y - lo);
    unsigned o6 = (unsigned)(ib.z - lo), o7 = (unsigned)(ib.w - lo);
    if (o0 < RS) atomicAdd(&h[o0], wa.x);
    if (o1 < RS) atomicAdd(&h[o1], wa.y);
    if (o2 < RS) atomicAdd(&h[o2], wa.z);
    if (o3 < RS) atomicAdd(&h[o3], wa.w);
    if (o4 < RS) atomicAdd(&h[o4], wb.x);
    if (o5 < RS) atomicAdd(&h[o5], wb.y);
    if (o6 < RS) atomicAdd(&h[o6], wb.z);
    if (o7 < RS) atomicAdd(&h[o7], wb.w);
  }
  for (; q < q1; q += 1024) {
    int4 idx = ei4[q];
    float4 w = ew4[q];
    unsigned o0 = (unsigned)(idx.x - lo), o1 = (unsigned)(idx.y - lo);
    unsigned o2 = (unsigned)(idx.z - lo), o3 = (unsigned)(idx.w - lo);
    if (o0 < RS) atomicAdd(&h[o0], w.x);
    if (o1 < RS) atomicAdd(&h[o1], w.y);
    if (o2 < RS) atomicAdd(&h[o2], w.z);
    if (o3 < RS) atomicAdd(&h[o3], w.w);
  }
  if (sl == BDEG - 1) {
    for (int e = (Q << 2) + threadIdx.x; e < E_; e += 1024) {
      unsigned off = (unsigned)(ei[e] - lo);
      if (off < RS) atomicAdd(&h[off], ew[e]);
    }
  }
  __syncthreads();
  __half* dst = slab + ((size_t)r * BDEG + sl) * RS;
  for (int i = threadIdx.x; i < used; i += 1024) dst[i] = __float2half(h[i]);
}

__global__ void k_node(const float* __restrict__ x, const float* __restrict__ y,
                       const void* __restrict__ maskp, const int* __restrict__ flag,
                       const __half* __restrict__ slab, int2* __restrict__ ninfo,
                       __half* __restrict__ p16, float* __restrict__ Hg,
                       float* __restrict__ cnt, unsigned* __restrict__ bitvec, int Nn) {
  __shared__ float scnt[32], sdiag[32];
  if (threadIdx.x < 32) { scnt[threadIdx.x] = 0.f; sdiag[threadIdx.x] = 0.f; }
  __syncthreads();
  int n = blockIdx.x * blockDim.x + threadIdx.x;
  bool inb = (n < Nn);
  bool byteMask = (*flag != 0);
  bool msk = false;
  if (inb)
    msk = byteMask ? (((const unsigned char*)maskp)[n] != 0)
                   : (((const int*)maskp)[n] != 0);
  // ballot-pack the row mask: 1 bit/node. All lanes participate (blockDim=256 -> full waves).
  unsigned long long bm = __ballot(msk);
  if ((threadIdx.x & 63) == 0)
    ((unsigned long long*)bitvec)[n >> 6] = bm;
  if (inb) {
    const __half* sl = slab + ((size_t)(n / RS) * BDEG) * RS + (n % RS);
    float d = 0.f;
    #pragma unroll 5
    for (int bb = 0; bb < BDEG; ++bb) d += __half2float(sl[(size_t)bb * RS]);
    float dinv = rsqrtf(d + 1.0f);   // +1 = self-loop weight
    int a = -1;
    if (msk) {
      const float4* yi = (const float4*)(y + (size_t)n * 32);
      #pragma unroll
      for (int q = 0; q < 8; ++q) {
        float4 v = yi[q];
        if (v.x == 1.f) a = q * 4 + 0;
        if (v.y == 1.f) a = q * 4 + 1;
        if (v.z == 1.f) a = q * 4 + 2;
        if (v.w == 1.f) a = q * 4 + 3;
      }
      atomicAdd(&scnt[a], 1.f);
      atomicAdd(&sdiag[a], dinv * dinv);   // masked self-loop hits only H[a][a]
    } else {
      const float4* xi = (const float4*)(x + (size_t)n * 32);
      float xs[32];
      #pragma unroll
      for (int q = 0; q < 8; ++q) {
        float4 v = xi[q];
        xs[q*4+0] = v.x; xs[q*4+1] = v.y; xs[q*4+2] = v.z; xs[q*4+3] = v.w;
      }
      float mx = -3.4e38f;
      #pragma unroll
      for (int i = 0; i < 32; ++i) mx = fmaxf(mx, xs[i]);
      float s = 0.f;
      #pragma unroll
      for (int i = 0; i < 32; ++i) { xs[i] = __expf(xs[i] - mx); s += xs[i]; }
      float inv = 1.f / s;
      union { short sh[32]; int4 v[4]; } u;
      #pragma unroll
      for (int i = 0; i < 32; ++i)
        u.sh[i] = __half_as_short(__float2half(xs[i] * inv));
      int4* po = (int4*)(p16 + (size_t)n * 32);
      #pragma unroll
      for (int q = 0; q < 4; ++q) po[q] = u.v[q];
    }
    int2 ni; ni.x = __float_as_int(dinv); ni.y = a;
    ninfo[n] = ni;
  }
  __syncthreads();
  if (threadIdx.x < 32) {
    if (scnt[threadIdx.x] != 0.f) atomicAdd(&cnt[threadIdx.x], scnt[threadIdx.x]);
    if (sdiag[threadIdx.x] != 0.f) atomicAdd(&Hg[threadIdx.x * 33], sdiag[threadIdx.x]);
  }
}

// Edge pass: row-mask bit from LDS bitvector gates ONE gather (ninfo[r]); every active
// edge becomes an 8B record {c<<5|a, dinv_r*w}; per-bucket contiguous span reserved with one
// global atomic, then direct scattered flush (stores are posted -- R18).
// NOTE: single-quad body on purpose -- R14's 2-quad unroll raised VGPR 24->36 and regressed.
__global__ __launch_bounds__(1024) void
k_bucket(const int* __restrict__ ei, const float* __restrict__ ew,
         const int2* __restrict__ ninfo, const unsigned* __restrict__ bitvec,
         int2* __restrict__ gBucket, int* __restrict__ gCnt, int E_) {
  __shared__ int2 list[LCAP];
  __shared__ int lcnt;
  __shared__ int bcnt[NBKTMAX];
  __shared__ int gbase[NBKTMAX];
  __shared__ int bplace[NBKTMAX];
  __shared__ unsigned sbv[BVW];
  if (threadIdx.x == 0) lcnt = 0;
  if (threadIdx.x < NBKTMAX) { bcnt[threadIdx.x] = 0; bplace[threadIdx.x] = 0; }
  for (int i = threadIdx.x; i < BVW; i += 1024) sbv[i] = bitvec[i];
  __syncthreads();
  int E4 = E_ >> 2;
  int q0 = (int)((long long)E4 * blockIdx.x / NSC);
  int q1 = (int)((long long)E4 * (blockIdx.x + 1) / NSC);
  for (int q = q0 + threadIdx.x; q < q1; q += 1024) {
    int4 rr = ((const int4*)ei)[q];
    int4 cc = ((const int4*)(ei + E_))[q];
    float4 ww = ((const float4*)ew)[q];
    int rs[4] = {rr.x, rr.y, rr.z, rr.w};
    int cs[4] = {cc.x, cc.y, cc.z, cc.w};
    float wv[4] = {ww.x, ww.y, ww.z, ww.w};
    bool act[4];
    #pragma unroll
    for (int k = 0; k < 4; ++k)
      act[k] = (sbv[(unsigned)rs[k] >> 5] >> (rs[k] & 31)) & 1;
    int2 nr[4];
    #pragma unroll
    for (int k = 0; k < 4; ++k)
      if (act[k]) nr[k] = ninfo[rs[k]];
    #pragma unroll
    for (int k = 0; k < 4; ++k) {
      if (act[k]) {
        float val = __int_as_float(nr[k].x) * wv[k];
        int pos = atomicAdd(&lcnt, 1);
        if (pos < LCAP) list[pos] = make_int2((cs[k] << 5) | nr[k].y, __float_as_int(val));
      }
    }
  }
  if (blockIdx.x == NSC - 1) {   // tail edges
    for (int e = (E4 << 2) + threadIdx.x; e < E_; e += 1024) {
      int r = ei[e];
      if (!((sbv[(unsigned)r >> 5] >> (r & 31)) & 1)) continue;
      int2 nr = ninfo[r];
      int c = ei[E_ + e];
      float val = __int_as_float(nr.x) * ew[e];
      int pos = atomicAdd(&lcnt, 1);
      if (pos < LCAP) list[pos] = make_int2((c << 5) | nr.y, __float_as_int(val));
    }
  }
  __syncthreads();
  int nl = min(lcnt, LCAP);
  for (int i = threadIdx.x; i < nl; i += 1024)
    atomicAdd(&bcnt[(list[i].x >> 5) / W], 1);
  __syncthreads();
  if (threadIdx.x < NBKTMAX) {
    int n = bcnt[threadIdx.x];
    gbase[threadIdx.x] = (n > 0) ? atomicAdd(&gCnt[threadIdx.x], n) : 0;
  }
  __syncthreads();
  for (int i = threadIdx.x; i < nl; i += 1024) {
    int2 rec = list[i];
    int bkt = (rec.x >> 5) / W;
    int slot = atomicAdd(&bplace[bkt], 1);
    int dst = gbase[bkt] + slot;
    if (dst < BCAP) gBucket[(size_t)bkt * BCAP + dst] = rec;
  }
}

// Bucket k: stage dinv/label for the 200 contiguous cols; wave-0 ballot-scan compacts the
// UNMASKED cols (cidx/cmap, ~100 of 200); records * dinv_c routed: masked col -> H32 tile,
// unmasked -> compacted TlocT[a][cmap]; p16 staged compacted plocT[b][j]; gemm over j<nU.
// Rounding per-term matches R15: record val = dinv_r*w, then *dinv_c here = (dr*w)*dc.
__global__ __launch_bounds__(1024) void
k_process(const int2* __restrict__ gBucket, const int* __restrict__ gCnt,
          const int2* __restrict__ ninfo, const __half* __restrict__ p16,
          float* __restrict__ procSlab, int Nn) {
  __shared__ float TlocT[32 * W];        // [a][j] compacted, stride W floats
  __shared__ __half plocT[32 * PPAD];    // [b][j] compacted, stride 204 halfs
  __shared__ float H32[1024];            // masked-col contributions H[a][b]
  __shared__ float ldin[W];              // dinv by ORIGINAL col index
  __shared__ int   llab[W];              // label by ORIGINAL col index (-1 = unmasked)
  __shared__ short cmap[W];              // orig col -> compact idx (valid where llab<0)
  __shared__ short cidx[W];              // compact idx -> orig col
  __shared__ int   nUs;
  int k = blockIdx.x;
  int c0 = k * W;
  int Wb = min(c0 + W, Nn) - c0;         // <=0 for out-of-range buckets (still write zeros)
  H32[threadIdx.x] = 0.f;
  if ((int)threadIdx.x < Wb) {
    int2 ni = ninfo[c0 + threadIdx.x];
    ldin[threadIdx.x] = __int_as_float(ni.x);
    llab[threadIdx.x] = ni.y;
  }
  if (threadIdx.x == 0) nUs = 0;
  __syncthreads();
  // wave 0: deterministic ballot-scan compaction of unmasked cols; others: zero TlocT
  if (threadIdx.x < 64) {
    int base = 0;
    for (int ch = 0; ch < W; ch += 64) {
      int j = ch + threadIdx.x;
      bool u = (j < Wb) && (llab[j] < 0);
      unsigned long long m = __ballot(u);
      int p = base + __popcll(m & ((1ull << threadIdx.x) - 1ull));
      if (u) { cmap[j] = (short)p; cidx[p] = (short)j; }
      base += (int)__popcll(m);
    }
    if (threadIdx.x == 0) nUs = base;
  }
  for (int i = threadIdx.x; i < 32 * W; i += 1024) TlocT[i] = 0.f;
  __syncthreads();
  int nU = nUs;
  if (Wb > 0) {
    for (int i = threadIdx.x; i < nU * 32; i += 1024) {
      int j = i >> 5, b = i & 31;
      plocT[b * PPAD + j] = p16[(size_t)(c0 + cidx[j]) * 32 + b];
    }
    int n = min(gCnt[k], BCAP);
    const int2* bk = gBucket + (size_t)k * BCAP;
    for (int i = threadIdx.x; i < n; i += 1024) {
      int2 rec = bk[i];
      int cl = (rec.x >> 5) - c0;
      int a = rec.x & 31;
      float v = __int_as_float(rec.y) * ldin[cl];
      int b = llab[cl];
      if (b >= 0) atomicAdd(&H32[a * 32 + b], v);
      else        atomicAdd(&TlocT[a * W + cmap[cl]], v);
    }
  }
  __syncthreads();
  int a = threadIdx.x >> 5;
  int b = threadIdx.x & 31;
  float acc0 = 0.f, acc1 = 0.f, acc2 = 0.f, acc3 = 0.f;
  int c = 0;
  for (; c + 3 < nU; c += 4) {
    float4 tv = *(const float4*)&TlocT[a * W + c];
    short4 ps = *(const short4*)&plocT[b * PPAD + c];
    acc0 += tv.x * __half2float(__short_as_half(ps.x));
    acc1 += tv.y * __half2float(__short_as_half(ps.y));
    acc2 += tv.z * __half2float(__short_as_half(ps.z));
    acc3 += tv.w * __half2float(__short_as_half(ps.w));
  }
  for (; c < nU; ++c)
    acc0 += TlocT[a * W + c] * __half2float(plocT[b * PPAD + c]);
  procSlab[(size_t)k * 1024 + threadIdx.x] =
      (acc0 + acc1) + (acc2 + acc3) + H32[threadIdx.x];
}

// Fused reduce + Sinkhorn: NRED blocks each reduce RPER slabs to a partial; the LAST block
// (threadfence + device atomic counter) re-reads the partials and runs Sinkhorn. Summation
// order identical to the old k_red + k_sinkhorn pair -> bitwise identical output.
__global__ __launch_bounds__(1024) void
k_redsink(const float* __restrict__ allSlabs, float* red,
          const float* __restrict__ cnt, float* __restrict__ out, int* done) {
  int t = threadIdx.x;
  int k0 = blockIdx.x * RPER;
  int k1 = min(k0 + RPER, NTOT);
  float s = 0.f;
  for (int k = k0; k < k1; ++k) s += allSlabs[(size_t)k * 1024 + t];
  red[(size_t)blockIdx.x * 1024 + t] = s;
  __threadfence();                       // make partial visible device-wide (release)
  __shared__ int lastBlk;
  if (t == 0) lastBlk = (atomicAdd(done, 1) == NRED - 1) ? 1 : 0;
  __syncthreads();
  if (!lastBlk) return;
  __threadfence();                       // order partial re-reads after the counter (acquire)
  __shared__ float sHH[1024];
  float s2 = 0.f;
  #pragma unroll
  for (int k = 0; k < NRED; ++k) s2 += red[(size_t)k * 1024 + t];
  sHH[t] = s2;
  __syncthreads();
  int j = t;
  if (j >= 32) return;
  float cj = cnt[j];
  float Hcol[32], Hrow[32];
  #pragma unroll
  for (int i = 0; i < 32; ++i) Hcol[i] = sHH[i * 32 + j];
  #pragma unroll
  for (int i = 0; i < 32; ++i) Hcol[i] /= __shfl(cj, i);   // H0[i][j]
  #pragma unroll
  for (int k = 0; k < 32; ++k) Hrow[k] = sHH[j * 32 + k] / cj;
  float u = 1.f, v = 1.f;
  for (int it = 0; it < 40; ++it) {
    float a0 = 0.f, a1 = 0.f, a2 = 0.f, a3 = 0.f;
    #pragma unroll
    for (int i = 0; i < 32; i += 4) {
      a0 += Hcol[i+0] * __shfl(u, i+0);
      a1 += Hcol[i+1] * __shfl(u, i+1);
      a2 += Hcol[i+2] * __shfl(u, i+2);
      a3 += Hcol[i+3] * __shfl(u, i+3);
    }
    v = 1.f / ((a0 + a1) + (a2 + a3));
    a0 = a1 = a2 = a3 = 0.f;
    #pragma unroll
    for (int k = 0; k < 32; k += 4) {
      a0 += Hrow[k+0] * __shfl(v, k+0);
      a1 += Hrow[k+1] * __shfl(v, k+1);
      a2 += Hrow[k+2] * __shfl(v, k+2);
      a3 += Hrow[k+3] * __shfl(v, k+3);
    }
    u = 1.f / ((a0 + a1) + (a2 + a3));
  }
  // final H = diag(u) H0 diag(v); row-norm last matches reference body order
  #pragma unroll
  for (int i = 0; i < 32; ++i) out[i * 32 + j] = __shfl(u, i) * Hcol[i] * v;
}

extern "C" void kernel_launch(void* const* d_in, const int* in_sizes, int n_in,
                              void* d_out, int out_size, void* d_ws, size_t ws_size,
                              hipStream_t stream) {
  const int*   ei   = (const int*)d_in[0];
  const float* ew   = (const float*)d_in[1];
  const float* x    = (const float*)d_in[2];
  const float* y    = (const float*)d_in[3];
  const void*  mask = d_in[4];
  float* out = (float*)d_out;
  int E_ = in_sizes[1];
  int Nn = in_sizes[2] / 32;
  int R = (Nn + RS - 1) / RS;

  char* ws = (char*)d_ws;
  size_t o = 0;
  float* cnt = (float*)(ws + o);    o += 128;
  int*   flag = (int*)(ws + o);     o += 128;   // flag[0]=mask dtype, flag[4]=done counter
  int*   gCnt = (int*)(ws + o);     o += NBKTMAX * 4;
  // contiguous copy region: Hg(1) | procSlab(NPR)
  float* allSlabs = (float*)(ws + o);
  float* Hg       = allSlabs;
  float* procSlab = allSlabs + 1024;
  o += (size_t)NTOT * 4096;
  float* red = (float*)(ws + o);    o += (size_t)NRED * 4096;
  int2*  gBucket = (int2*)(ws + o); o += (size_t)NBKTMAX * BCAP * 8;
  __half* slab = (__half*)(ws + o); o += (size_t)R * BDEG * RS * 2;
  int2*  ninfo = (int2*)(ws + o);   o += (size_t)Nn * 8;
  __half* p16 = (__half*)(ws + o);  o += (size_t)Nn * 64;
  unsigned* gbv = (unsigned*)(ws + o); o += (size_t)BVW * 4;

  int nb = (Nn + 255) / 256;
  k_deg<<<R * BDEG, 1024, 0, stream>>>(ei, ew, slab, (const unsigned char*)mask,
                                       flag, Hg, cnt, gCnt, E_, R, Nn);
  k_node<<<nb, 256, 0, stream>>>(x, y, mask, flag, slab, ninfo, p16, Hg, cnt, gbv, Nn);
  k_bucket<<<NSC, 1024, 0, stream>>>(ei, ew, ninfo, gbv, gBucket, gCnt, E_);
  k_process<<<NPR, 1024, 0, stream>>>(gBucket, gCnt, ninfo, p16, procSlab, Nn);
  k_redsink<<<NRED, 1024, 0, stream>>>(allSlabs, red, cnt, out, flag + 4);
}

// Round 9
// 215.779 us; speedup vs baseline: 1.0567x; 1.0567x over previous
//
#include <hip/hip_runtime.h>
#include <hip/hip_fp16.h>

// CompatibilityLayer (R21 base + R23: direct-flush k_bucket, separate k_red/k_sinkhorn):
//   k_deg: range-binned LDS histograms (160KB LDS, R=3 x 80 slices; sniff flag aliased onto
//          h[0]); (r,sl)->blockIdx remap puts the 3 range-passes of one edge slice on the
//          SAME XCD (b%8) so passes 2-3 hit its 4MB L2. Block 0 zeros Hg/cnt/gCnt.
//   k_node: reduce deg slabs -> dinv; label/cnt/diag (masked); softmax -> p16 (unmasked);
//           ballot-packs the row mask into a global bitvector (1 bit/node)
//   k_bucket: stages 12.8KB mask bitvector in LDS; predicates the single ninfo[r] gather on
//             it. ALL active edges -> records {c<<5|a, dinv_r*w}; per-bucket span reserved
//             with ONE global atomic, then DIRECT scattered flush (counting-sort deleted --
//             R18: scattered stores are posted/free; the sort's barriers were pure overhead).
//   k_process: wave-0 ballot-scan compacts unmasked cols (~100 of 200); records * dinv_c
//              routed: masked col -> H32 tile, unmasked -> compacted TlocT; gemm over j<nU.
//   k_red: 513 slabs -> 16 partials;  k_sinkhorn: reduce + Sinkhorn (converges << 40 iters).
//          SEPARATE kernels on purpose (R22 post-mortem below).
// Fixed ~100us/replay harness overhead (41us = 256MB workspace re-poison fill at 82% HBM).
// CALIBRATION (hard-won):
//   R15/R16: random divergent LOADS ~5.5-6us per 1M lane-transactions (the currency).
//   R18: scattered STORES are posted/free at ~50% occupancy -- coalescing them was a null.
//   R19: random GLOBAL ATOMICS ~52ns/op (3.2M = 167us!); each RMW write-throughs a line to
//        HBM. NEVER use global atomics for histograms; LDS-privatize.
//   R21: k_deg is DS-atomic/issue-bound, not scan-BW-bound -- byte-count levers null there.
//   R22: __threadfence() (device-scope) costs tens of us on gfx950 -- per-XCD L2s are
//        non-coherent, so the fence forces L2 writeback/inv. Fused last-block-finishes
//        reduce+Sinkhorn ran 72us doing nothing (FETCH 1MB, VALU 0.05%). Separate launches
//        (~3-5us gap) are CHEAPER than one cross-block fence. Never fuse across a fence.
// R14 lesson: deeper unrolls raise VGPR, drop occupancy, and REGRESS k_bucket.

#define RS 40960          // deg histogram range (160 KB LDS -- full CU, 1 block/CU in k_deg)
#define BDEG 80           // deg slices; k_deg grid = R*BDEG = 240 (R=3); 8 | R*BDEG required
#define W 200             // cols per bucket
#define NBKTMAX 512       // bucket slots (runtime nbkt = ceil(Nn/W) <= 512 for Nn <= 102400)
#define BCAP 4608         // per-bucket record capacity (avg ~3200, sd ~57, +24 sigma)
#define LCAP 4096         // per-block LDS record list (avg ~3125, sd ~40, +24 sigma)
#define NSC 512           // k_bucket blocks
#define NPR NBKTMAX       // k_process blocks
#define NTOT (1 + NPR)    // 513 slab copies: Hg | procSlab
#define NRED 16
#define RPER ((NTOT + NRED - 1) / NRED)
#define PPAD 204          // plocT stride in halfs (8B-aligned vectors, conflict-friendly)
#define BVW 3200          // mask bitvector words (covers Nn <= 102400 = NBKTMAX*W)

__global__ __launch_bounds__(1024) void
k_deg(const int* __restrict__ ei, const float* __restrict__ ew,
      __half* __restrict__ slab, const unsigned char* __restrict__ mask_bytes,
      int* __restrict__ flag, float* __restrict__ Hg, float* __restrict__ cnt,
      int* __restrict__ gCnt, int E_, int R, int Nn) {
  __shared__ float h[RS];              // exactly 160 KiB -- no other shared vars allowed
  if (blockIdx.x == 0) {
    Hg[threadIdx.x] = 0.f;
    if (threadIdx.x < 32) cnt[threadIdx.x] = 0.f;
    if (threadIdx.x < NBKTMAX) gCnt[threadIdx.x] = 0;
    // mask dtype sniff: int32 0/1 has zero bytes at i*4+{1,2,3}; bool byte-array doesn't.
    // Flag lives in h[0] (as int) -- sniff completes before the histogram zero pass.
    int* hi = (int*)h;
    if (threadIdx.x == 0) hi[0] = 0;
    __syncthreads();
    int acc = mask_bytes[threadIdx.x * 4 + 1] | mask_bytes[threadIdx.x * 4 + 2]
            | mask_bytes[threadIdx.x * 4 + 3];
    if (acc) atomicOr(&hi[0], 1);
    __syncthreads();
    if (threadIdx.x == 0) *flag = (hi[0] != 0) ? 1 : 0;
  }
  // XCD-aware remap: the R blocks sharing edge slice sl get blockIdx == same value mod 8,
  // i.e. the same XCD under round-robin dispatch -> slice reads 2..R hit that XCD's L2.
  int g = blockIdx.x >> 3, xx = blockIdx.x & 7;
  int r = g % R;
  int sl = xx + 8 * (g / R);
  int lo = r * RS;
  int used = min(RS, Nn - lo);         // partial last range: only these bins are ever read
  for (int i = threadIdx.x; i < used; i += 1024) h[i] = 0.f;
  __syncthreads();
  int Q = E_ >> 2;
  int q0 = (int)((long long)Q * sl / BDEG);
  int q1 = (int)((long long)Q * (sl + 1) / BDEG);
  const int4* ei4 = (const int4*)ei;
  const float4* ew4 = (const float4*)ew;
  int q = q0 + threadIdx.x;
  for (; q + 1024 < q1; q += 2048) {       // 2-quad unroll: 8 edges in flight
    int4 ia = ei4[q], ib = ei4[q + 1024];
    float4 wa = ew4[q], wb = ew4[q + 1024];
    unsigned o0 = (unsigned)(ia.x - lo), o1 = (unsigned)(ia.y - lo);
    unsigned o2 = (unsigned)(ia.z - lo), o3 = (unsigned)(ia.w - lo);
    unsigned o4 = (unsigned)(ib.x - lo), o5 = (unsigned)(ib.y - lo);
    unsigned o6 = (unsigned)(ib.z - lo), o7 = (unsigned)(ib.w - lo);
    if (o0 < RS) atomicAdd(&h[o0], wa.x);
    if (o1 < RS) atomicAdd(&h[o1], wa.y);
    if (o2 < RS) atomicAdd(&h[o2], wa.z);
    if (o3 < RS) atomicAdd(&h[o3], wa.w);
    if (o4 < RS) atomicAdd(&h[o4], wb.x);
    if (o5 < RS) atomicAdd(&h[o5], wb.y);
    if (o6 < RS) atomicAdd(&h[o6], wb.z);
    if (o7 < RS) atomicAdd(&h[o7], wb.w);
  }
  for (; q < q1; q += 1024) {
    int4 idx = ei4[q];
    float4 w = ew4[q];
    unsigned o0 = (unsigned)(idx.x - lo), o1 = (unsigned)(idx.y - lo);
    unsigned o2 = (unsigned)(idx.z - lo), o3 = (unsigned)(idx.w - lo);
    if (o0 < RS) atomicAdd(&h[o0], w.x);
    if (o1 < RS) atomicAdd(&h[o1], w.y);
    if (o2 < RS) atomicAdd(&h[o2], w.z);
    if (o3 < RS) atomicAdd(&h[o3], w.w);
  }
  if (sl == BDEG - 1) {
    for (int e = (Q << 2) + threadIdx.x; e < E_; e += 1024) {
      unsigned off = (unsigned)(ei[e] - lo);
      if (off < RS) atomicAdd(&h[off], ew[e]);
    }
  }
  __syncthreads();
  __half* dst = slab + ((size_t)r * BDEG + sl) * RS;
  for (int i = threadIdx.x; i < used; i += 1024) dst[i] = __float2half(h[i]);
}

__global__ void k_node(const float* __restrict__ x, const float* __restrict__ y,
                       const void* __restrict__ maskp, const int* __restrict__ flag,
                       const __half* __restrict__ slab, int2* __restrict__ ninfo,
                       __half* __restrict__ p16, float* __restrict__ Hg,
                       float* __restrict__ cnt, unsigned* __restrict__ bitvec, int Nn) {
  __shared__ float scnt[32], sdiag[32];
  if (threadIdx.x < 32) { scnt[threadIdx.x] = 0.f; sdiag[threadIdx.x] = 0.f; }
  __syncthreads();
  int n = blockIdx.x * blockDim.x + threadIdx.x;
  bool inb = (n < Nn);
  bool byteMask = (*flag != 0);
  bool msk = false;
  if (inb)
    msk = byteMask ? (((const unsigned char*)maskp)[n] != 0)
                   : (((const int*)maskp)[n] != 0);
  // ballot-pack the row mask: 1 bit/node. All lanes participate (blockDim=256 -> full waves).
  unsigned long long bm = __ballot(msk);
  if ((threadIdx.x & 63) == 0)
    ((unsigned long long*)bitvec)[n >> 6] = bm;
  if (inb) {
    const __half* sl = slab + ((size_t)(n / RS) * BDEG) * RS + (n % RS);
    float d = 0.f;
    #pragma unroll 5
    for (int bb = 0; bb < BDEG; ++bb) d += __half2float(sl[(size_t)bb * RS]);
    float dinv = rsqrtf(d + 1.0f);   // +1 = self-loop weight
    int a = -1;
    if (msk) {
      const float4* yi = (const float4*)(y + (size_t)n * 32);
      #pragma unroll
      for (int q = 0; q < 8; ++q) {
        float4 v = yi[q];
        if (v.x == 1.f) a = q * 4 + 0;
        if (v.y == 1.f) a = q * 4 + 1;
        if (v.z == 1.f) a = q * 4 + 2;
        if (v.w == 1.f) a = q * 4 + 3;
      }
      atomicAdd(&scnt[a], 1.f);
      atomicAdd(&sdiag[a], dinv * dinv);   // masked self-loop hits only H[a][a]
    } else {
      const float4* xi = (const float4*)(x + (size_t)n * 32);
      float xs[32];
      #pragma unroll
      for (int q = 0; q < 8; ++q) {
        float4 v = xi[q];
        xs[q*4+0] = v.x; xs[q*4+1] = v.y; xs[q*4+2] = v.z; xs[q*4+3] = v.w;
      }
      float mx = -3.4e38f;
      #pragma unroll
      for (int i = 0; i < 32; ++i) mx = fmaxf(mx, xs[i]);
      float s = 0.f;
      #pragma unroll
      for (int i = 0; i < 32; ++i) { xs[i] = __expf(xs[i] - mx); s += xs[i]; }
      float inv = 1.f / s;
      union { short sh[32]; int4 v[4]; } u;
      #pragma unroll
      for (int i = 0; i < 32; ++i)
        u.sh[i] = __half_as_short(__float2half(xs[i] * inv));
      int4* po = (int4*)(p16 + (size_t)n * 32);
      #pragma unroll
      for (int q = 0; q < 4; ++q) po[q] = u.v[q];
    }
    int2 ni; ni.x = __float_as_int(dinv); ni.y = a;
    ninfo[n] = ni;
  }
  __syncthreads();
  if (threadIdx.x < 32) {
    if (scnt[threadIdx.x] != 0.f) atomicAdd(&cnt[threadIdx.x], scnt[threadIdx.x]);
    if (sdiag[threadIdx.x] != 0.f) atomicAdd(&Hg[threadIdx.x * 33], sdiag[threadIdx.x]);
  }
}

// Edge pass: row-mask bit from LDS bitvector gates ONE gather (ninfo[r]); every active
// edge becomes an 8B record {c<<5|a, dinv_r*w}; per-bucket contiguous span reserved with one
// global atomic, then direct scattered flush (stores are posted -- R18).
// NOTE: single-quad body on purpose -- R14's 2-quad unroll raised VGPR 24->36 and regressed.
__global__ __launch_bounds__(1024) void
k_bucket(const int* __restrict__ ei, const float* __restrict__ ew,
         const int2* __restrict__ ninfo, const unsigned* __restrict__ bitvec,
         int2* __restrict__ gBucket, int* __restrict__ gCnt, int E_) {
  __shared__ int2 list[LCAP];
  __shared__ int lcnt;
  __shared__ int bcnt[NBKTMAX];
  __shared__ int gbase[NBKTMAX];
  __shared__ int bplace[NBKTMAX];
  __shared__ unsigned sbv[BVW];
  if (threadIdx.x == 0) lcnt = 0;
  if (threadIdx.x < NBKTMAX) { bcnt[threadIdx.x] = 0; bplace[threadIdx.x] = 0; }
  for (int i = threadIdx.x; i < BVW; i += 1024) sbv[i] = bitvec[i];
  __syncthreads();
  int E4 = E_ >> 2;
  int q0 = (int)((long long)E4 * blockIdx.x / NSC);
  int q1 = (int)((long long)E4 * (blockIdx.x + 1) / NSC);
  for (int q = q0 + threadIdx.x; q < q1; q += 1024) {
    int4 rr = ((const int4*)ei)[q];
    int4 cc = ((const int4*)(ei + E_))[q];
    float4 ww = ((const float4*)ew)[q];
    int rs[4] = {rr.x, rr.y, rr.z, rr.w};
    int cs[4] = {cc.x, cc.y, cc.z, cc.w};
    float wv[4] = {ww.x, ww.y, ww.z, ww.w};
    bool act[4];
    #pragma unroll
    for (int k = 0; k < 4; ++k)
      act[k] = (sbv[(unsigned)rs[k] >> 5] >> (rs[k] & 31)) & 1;
    int2 nr[4];
    #pragma unroll
    for (int k = 0; k < 4; ++k)
      if (act[k]) nr[k] = ninfo[rs[k]];
    #pragma unroll
    for (int k = 0; k < 4; ++k) {
      if (act[k]) {
        float val = __int_as_float(nr[k].x) * wv[k];
        int pos = atomicAdd(&lcnt, 1);
        if (pos < LCAP) list[pos] = make_int2((cs[k] << 5) | nr[k].y, __float_as_int(val));
      }
    }
  }
  if (blockIdx.x == NSC - 1) {   // tail edges
    for (int e = (E4 << 2) + threadIdx.x; e < E_; e += 1024) {
      int r = ei[e];
      if (!((sbv[(unsigned)r >> 5] >> (r & 31)) & 1)) continue;
      int2 nr = ninfo[r];
      int c = ei[E_ + e];
      float val = __int_as_float(nr.x) * ew[e];
      int pos = atomicAdd(&lcnt, 1);
      if (pos < LCAP) list[pos] = make_int2((c << 5) | nr.y, __float_as_int(val));
    }
  }
  __syncthreads();
  int nl = min(lcnt, LCAP);
  for (int i = threadIdx.x; i < nl; i += 1024)
    atomicAdd(&bcnt[(list[i].x >> 5) / W], 1);
  __syncthreads();
  if (threadIdx.x < NBKTMAX) {
    int n = bcnt[threadIdx.x];
    gbase[threadIdx.x] = (n > 0) ? atomicAdd(&gCnt[threadIdx.x], n) : 0;
  }
  __syncthreads();
  for (int i = threadIdx.x; i < nl; i += 1024) {
    int2 rec = list[i];
    int bkt = (rec.x >> 5) / W;
    int slot = atomicAdd(&bplace[bkt], 1);
    int dst = gbase[bkt] + slot;
    if (dst < BCAP) gBucket[(size_t)bkt * BCAP + dst] = rec;
  }
}

// Bucket k: stage dinv/label for the 200 contiguous cols; wave-0 ballot-scan compacts the
// UNMASKED cols (cidx/cmap, ~100 of 200); records * dinv_c routed: masked col -> H32 tile,
// unmasked -> compacted TlocT[a][cmap]; p16 staged compacted plocT[b][j]; gemm over j<nU.
// Rounding per-term matches R15: record val = dinv_r*w, then *dinv_c here = (dr*w)*dc.
__global__ __launch_bounds__(1024) void
k_process(const int2* __restrict__ gBucket, const int* __restrict__ gCnt,
          const int2* __restrict__ ninfo, const __half* __restrict__ p16,
          float* __restrict__ procSlab, int Nn) {
  __shared__ float TlocT[32 * W];        // [a][j] compacted, stride W floats
  __shared__ __half plocT[32 * PPAD];    // [b][j] compacted, stride 204 halfs
  __shared__ float H32[1024];            // masked-col contributions H[a][b]
  __shared__ float ldin[W];              // dinv by ORIGINAL col index
  __shared__ int   llab[W];              // label by ORIGINAL col index (-1 = unmasked)
  __shared__ short cmap[W];              // orig col -> compact idx (valid where llab<0)
  __shared__ short cidx[W];              // compact idx -> orig col
  __shared__ int   nUs;
  int k = blockIdx.x;
  int c0 = k * W;
  int Wb = min(c0 + W, Nn) - c0;         // <=0 for out-of-range buckets (still write zeros)
  H32[threadIdx.x] = 0.f;
  if ((int)threadIdx.x < Wb) {
    int2 ni = ninfo[c0 + threadIdx.x];
    ldin[threadIdx.x] = __int_as_float(ni.x);
    llab[threadIdx.x] = ni.y;
  }
  if (threadIdx.x == 0) nUs = 0;
  __syncthreads();
  // wave 0: deterministic ballot-scan compaction of unmasked cols; others: zero TlocT
  if (threadIdx.x < 64) {
    int base = 0;
    for (int ch = 0; ch < W; ch += 64) {
      int j = ch + threadIdx.x;
      bool u = (j < Wb) && (llab[j] < 0);
      unsigned long long m = __ballot(u);
      int p = base + __popcll(m & ((1ull << threadIdx.x) - 1ull));
      if (u) { cmap[j] = (short)p; cidx[p] = (short)j; }
      base += (int)__popcll(m);
    }
    if (threadIdx.x == 0) nUs = base;
  }
  for (int i = threadIdx.x; i < 32 * W; i += 1024) TlocT[i] = 0.f;
  __syncthreads();
  int nU = nUs;
  if (Wb > 0) {
    for (int i = threadIdx.x; i < nU * 32; i += 1024) {
      int j = i >> 5, b = i & 31;
      plocT[b * PPAD + j] = p16[(size_t)(c0 + cidx[j]) * 32 + b];
    }
    int n = min(gCnt[k], BCAP);
    const int2* bk = gBucket + (size_t)k * BCAP;
    for (int i = threadIdx.x; i < n; i += 1024) {
      int2 rec = bk[i];
      int cl = (rec.x >> 5) - c0;
      int a = rec.x & 31;
      float v = __int_as_float(rec.y) * ldin[cl];
      int b = llab[cl];
      if (b >= 0) atomicAdd(&H32[a * 32 + b], v);
      else        atomicAdd(&TlocT[a * W + cmap[cl]], v);
    }
  }
  __syncthreads();
  int a = threadIdx.x >> 5;
  int b = threadIdx.x & 31;
  float acc0 = 0.f, acc1 = 0.f, acc2 = 0.f, acc3 = 0.f;
  int c = 0;
  for (; c + 3 < nU; c += 4) {
    float4 tv = *(const float4*)&TlocT[a * W + c];
    short4 ps = *(const short4*)&plocT[b * PPAD + c];
    acc0 += tv.x * __half2float(__short_as_half(ps.x));
    acc1 += tv.y * __half2float(__short_as_half(ps.y));
    acc2 += tv.z * __half2float(__short_as_half(ps.z));
    acc3 += tv.w * __half2float(__short_as_half(ps.w));
  }
  for (; c < nU; ++c)
    acc0 += TlocT[a * W + c] * __half2float(plocT[b * PPAD + c]);
  procSlab[(size_t)k * 1024 + threadIdx.x] =
      (acc0 + acc1) + (acc2 + acc3) + H32[threadIdx.x];
}

// Reduce NTOT contiguous copies (Hg | procSlab) -> NRED partials.
__global__ __launch_bounds__(1024) void
k_red(const float* __restrict__ allSlabs, float* __restrict__ red) {
  int k0 = blockIdx.x * RPER;
  int k1 = min(k0 + RPER, NTOT);
  float s = 0.f;
  for (int k = k0; k < k1; ++k) s += allSlabs[(size_t)k * 1024 + threadIdx.x];
  red[(size_t)blockIdx.x * 1024 + threadIdx.x] = s;
}

// Reduce NRED partials, then wave 0 runs Sinkhorn on scaling vectors:
// v = 1/(H0^T u), u = 1/(H0 v). 40 iters >> convergence.
__global__ __launch_bounds__(1024) void
k_sinkhorn(const float* __restrict__ red, const float* __restrict__ cnt,
           float* __restrict__ out) {
  __shared__ float sHH[1024];
  int t = threadIdx.x;
  float s = 0.f;
  #pragma unroll
  for (int k = 0; k < NRED; ++k) s += red[(size_t)k * 1024 + t];
  sHH[t] = s;
  __syncthreads();
  int j = t;
  if (j >= 32) return;
  float cj = cnt[j];
  float Hcol[32], Hrow[32];
  #pragma unroll
  for (int i = 0; i < 32; ++i) Hcol[i] = sHH[i * 32 + j];
  #pragma unroll
  for (int i = 0; i < 32; ++i) Hcol[i] /= __shfl(cj, i);   // H0[i][j]
  #pragma unroll
  for (int k = 0; k < 32; ++k) Hrow[k] = sHH[j * 32 + k] / cj;
  float u = 1.f, v = 1.f;
  for (int it = 0; it < 40; ++it) {
    float a0 = 0.f, a1 = 0.f, a2 = 0.f, a3 = 0.f;
    #pragma unroll
    for (int i = 0; i < 32; i += 4) {
      a0 += Hcol[i+0] * __shfl(u, i+0);
      a1 += Hcol[i+1] * __shfl(u, i+1);
      a2 += Hcol[i+2] * __shfl(u, i+2);
      a3 += Hcol[i+3] * __shfl(u, i+3);
    }
    v = 1.f / ((a0 + a1) + (a2 + a3));
    a0 = a1 = a2 = a3 = 0.f;
    #pragma unroll
    for (int k = 0; k < 32; k += 4) {
      a0 += Hrow[k+0] * __shfl(v, k+0);
      a1 += Hrow[k+1] * __shfl(v, k+1);
      a2 += Hrow[k+2] * __shfl(v, k+2);
      a3 += Hrow[k+3] * __shfl(v, k+3);
    }
    u = 1.f / ((a0 + a1) + (a2 + a3));
  }
  // final H = diag(u) H0 diag(v); row-norm last matches reference body order
  #pragma unroll
  for (int i = 0; i < 32; ++i) out[i * 32 + j] = __shfl(u, i) * Hcol[i] * v;
}

extern "C" void kernel_launch(void* const* d_in, const int* in_sizes, int n_in,
                              void* d_out, int out_size, void* d_ws, size_t ws_size,
                              hipStream_t stream) {
  const int*   ei   = (const int*)d_in[0];
  const float* ew   = (const float*)d_in[1];
  const float* x    = (const float*)d_in[2];
  const float* y    = (const float*)d_in[3];
  const void*  mask = d_in[4];
  float* out = (float*)d_out;
  int E_ = in_sizes[1];
  int Nn = in_sizes[2] / 32;
  int R = (Nn + RS - 1) / RS;

  char* ws = (char*)d_ws;
  size_t o = 0;
  float* cnt = (float*)(ws + o);    o += 128;
  int*   flag = (int*)(ws + o);     o += 128;
  int*   gCnt = (int*)(ws + o);     o += NBKTMAX * 4;
  // contiguous copy region: Hg(1) | procSlab(NPR)
  float* allSlabs = (float*)(ws + o);
  float* Hg       = allSlabs;
  float* procSlab = allSlabs + 1024;
  o += (size_t)NTOT * 4096;
  float* red = (float*)(ws + o);    o += (size_t)NRED * 4096;
  int2*  gBucket = (int2*)(ws + o); o += (size_t)NBKTMAX * BCAP * 8;
  __half* slab = (__half*)(ws + o); o += (size_t)R * BDEG * RS * 2;
  int2*  ninfo = (int2*)(ws + o);   o += (size_t)Nn * 8;
  __half* p16 = (__half*)(ws + o);  o += (size_t)Nn * 64;
  unsigned* gbv = (unsigned*)(ws + o); o += (size_t)BVW * 4;

  int nb = (Nn + 255) / 256;
  k_deg<<<R * BDEG, 1024, 0, stream>>>(ei, ew, slab, (const unsigned char*)mask,
                                       flag, Hg, cnt, gCnt, E_, R, Nn);
  k_node<<<nb, 256, 0, stream>>>(x, y, mask, flag, slab, ninfo, p16, Hg, cnt, gbv, Nn);
  k_bucket<<<NSC, 1024, 0, stream>>>(ei, ew, ninfo, gbv, gBucket, gCnt, E_);
  k_process<<<NPR, 1024, 0, stream>>>(gBucket, gCnt, ninfo, p16, procSlab, Nn);
  k_red<<<NRED, 1024, 0, stream>>>(allSlabs, red);
  k_sinkhorn<<<1, 1024, 0, stream>>>(red, cnt, out);
}